// Round 9
// baseline (103.798 us; speedup 1.0000x reference)
//
#include <hip/hip_runtime.h>
#include <math.h>

// Chamfer distance, B=4, H=W=128, HW=16384, threshold 0.1.
//
// r8 post-mortem: pdist was LDS-THROUGHPUT-bound (2 rows/lane -> 3
// ds_read_b128 per 4 cols vs 20 VALU; 16 waves/CU share ONE LDS unit:
// 576cy LDS vs 160cy SIMD per slot). That's why 2x waves + prefetch gave
// only the centering win. r9: 8 rows/lane (RG=512) cuts LDS cy/pair 4x to
// ~parity with the fp32 datapath; GPU kept full by splitting cols across
// blockIdx.z by PARITY of the absolute 64-col batch index, combined via
// atomicMin (131K atomics, negligible per r3). Correctness: each block
// excludes only cols provably worse than ITS OWN phase-A md (md_z >= true
// min, margin family proven absmax==0 in r6-r8) -> argmin col is never
// excludable by either block -> its parity-owner processes it; fmax(x+p,0)
// is monotone so atomicMin of per-part results == single-block bits.
//
// ws layout (~4.7 MB):
//   [0,128)    int segcounts[8][4]
//   [256,+2MB) float4 pts[8][HW]     segmented semi-dense (seg s at s*4096)
//   [+512KB)   uint minarr[8][HW]    d^2 bits, slot-indexed
//   [+2MB)     float4 sorted[8][HW]  (x, y, z, slot_bits) rho-bucket order
//   [+8.2KB)   int binstart[8][257]
//   [+32KB)    int hist[8][4][256]

#define B_ 4
#define HW_ 16384
#define THRESH 0.1f
#define BIGF 1e30f
#define EPS_ 1e-12f

#define SEGCAP 4096
#define NSEG 4
#define NBIN 256
#define BINSCALE 0.25f   // bin = min(255, rho*0.25); width 4, covers rho<1024
#define BINW 4.0f
#define RG 512           // rows per pdist block (8/lane: LDS amortization)
#define RPT 8            // rows per thread
#define NW 8             // waves per pdist block (512 threads)
#define AWIN 1024        // phase-A window (cols), 16 batches on the 64-grid
#define PD_NGRP 32       // 32 x 512 = 16384 row-slot coverage
#define MWS 520          // mW stride: 520%32=8 -> cross-wave reads 2-way max

// ---------------- compact + bin histogram (r6, proven) ----------------
__global__ __launch_bounds__(1024)
void compact_kernel(const float* __restrict__ in1, const float* __restrict__ in2,
                    int* __restrict__ segcounts, float4* __restrict__ pts,
                    uint4* __restrict__ minarr4, int* __restrict__ histG) {
    int seg = blockIdx.x, combo = blockIdx.y;
    int b = combo >> 1, s = combo & 1;
    int tid = threadIdx.x, lane = tid & 63, wid = tid >> 6;
    const float* in = s ? in2 : in1;
    int ibase = seg * SEGCAP + tid * 4;
    float4 v = ((const float4*)(in + b * HW_))[(unsigned)ibase >> 2];
    float w0 = v.x - THRESH, w1 = v.y - THRESH, w2 = v.z - THRESH, w3 = v.w - THRESH;
    int a0 = w0 > 0.f, a1 = w1 > 0.f, a2 = w2 > 0.f, a3 = w3 > 0.f;

    unsigned int bb = __float_as_uint(BIGF);
    minarr4[(unsigned)(combo * HW_ + ibase) >> 2] = make_uint4(bb, bb, bb, bb);

    __shared__ int hist[NBIN];
    if (tid < NBIN) hist[tid] = 0;

    int c = a0 + a1 + a2 + a3;
    int incl = c;
#pragma unroll
    for (int o = 1; o < 64; o <<= 1) {
        int x = __shfl_up(incl, o, 64);
        if (lane >= o) incl += x;
    }
    int wexcl = incl - c;
    __shared__ int wtot[16], wpre[17];
    if (lane == 63) wtot[wid] = incl;
    __syncthreads();                             // covers hist init too
    if (tid == 0) {
        int run = 0;
#pragma unroll
        for (int ww = 0; ww < 16; ++ww) { wpre[ww] = run; run += wtot[ww]; }
        wpre[16] = run;
    }
    __syncthreads();
    int off = wpre[wid] + wexcl;
    float4* dst = pts + combo * HW_ + seg * SEGCAP;
    float wv[4] = {w0, w1, w2, w3};
    int   av[4] = {a0, a1, a2, a3};
#pragma unroll
    for (int u = 0; u < 4; ++u) {
        if (av[u]) {
            int i = ibase + u;
            float qx = (float)(i >> 7) * wv[u];
            float qy = (float)(i & 127) * wv[u];
            float zz = qx * qx + qy * qy;
            dst[off] = make_float4(qx, qy, zz, 0.0f);
            int bin = min(NBIN - 1, (int)(sqrtf(zz) * BINSCALE));
            atomicAdd(&hist[bin], 1);
            ++off;
        }
    }
    if (tid == 0) segcounts[combo * 4 + seg] = wpre[16];
    __syncthreads();
    if (tid < NBIN)
        histG[(combo * NSEG + seg) * NBIN + tid] = hist[tid];
}

// ---------------- scatter: 1 block per (seg, combo) = 32 blocks (r6) -------
__global__ __launch_bounds__(512)
void scatter_kernel(const int* __restrict__ segcounts, const float4* __restrict__ pts,
                    const int* __restrict__ histG, float4* __restrict__ sorted,
                    int* __restrict__ binstartG) {
    int seg = blockIdx.x, combo = blockIdx.y;
    int tid = threadIdx.x;
    __shared__ int h[NSEG][NBIN];
    __shared__ int sc[NBIN];
    __shared__ int cur[NBIN];
    for (int i = tid; i < NSEG * NBIN; i += 512)
        h[i >> 8][i & 255] = histG[combo * NSEG * NBIN + i];
    __syncthreads();
    if (tid < NBIN) sc[tid] = h[0][tid] + h[1][tid] + h[2][tid] + h[3][tid];
    __syncthreads();
#pragma unroll
    for (int o = 1; o < NBIN; o <<= 1) {         // Hillis-Steele inclusive scan
        int v = (tid < NBIN && tid >= o) ? sc[tid - o] : 0;
        __syncthreads();
        if (tid < NBIN) sc[tid] += v;
        __syncthreads();
    }
    if (tid < NBIN) {
        int tot = h[0][tid] + h[1][tid] + h[2][tid] + h[3][tid];
        int excl = sc[tid] - tot;                // exclusive bin start
        int o2 = excl;
        for (int s2 = 0; s2 < seg; ++s2) o2 += h[s2][tid];   // seg-uniform
        cur[tid] = o2;
        if (seg == 0) binstartG[combo * (NBIN + 1) + tid] = excl;
    }
    if (seg == 0 && tid == 0)
        binstartG[combo * (NBIN + 1) + NBIN] = sc[NBIN - 1];  // n_active
    __syncthreads();
    int c = segcounts[combo * 4 + seg];
    const float4* src = pts + combo * HW_ + seg * SEGCAP;
    for (int i = tid; i < c; i += 512) {
        float4 p = src[i];
        int bin = min(NBIN - 1, (int)(sqrtf(p.z) * BINSCALE));
        int idx = atomicAdd(&cur[bin], 1);
        sorted[(size_t)combo * HW_ + idx] =
            make_float4(p.x, p.y, p.z, __uint_as_float((unsigned)(seg * SEGCAP + i)));
    }
}

// ---------------- pruned dist: 512 rows, 8 rows/lane, col-parity split ------
__global__ __launch_bounds__(512, 4)   // VGPR cap 128; ~32 row-state regs
void pdist_kernel(const float4* __restrict__ sorted, const int* __restrict__ binstart,
                  unsigned int* __restrict__ minarr) {
    int grp = blockIdx.x, combo = blockIdx.y, z = blockIdx.z;
    int tid = threadIdx.x, lane = tid & 63, w = tid >> 6;
    int tc = combo ^ 1;
    int n_from = binstart[combo * (NBIN + 1) + NBIN];
    int n_to   = binstart[tc * (NBIN + 1) + NBIN];
    if (n_from <= 0 || n_to <= 0) return;        // reduce_out emits sentinel
    int rbase = grp * RG;
    if (rbase >= n_from) return;                 // block-uniform

    const float4* __restrict__ rows = sorted + (size_t)combo * HW_;
    const float4* __restrict__ cols = sorted + (size_t)tc * HW_;

    float npx[RPT], npy[RPT], p2[RPT], m[RPT];
#pragma unroll
    for (int k = 0; k < RPT; ++k) {
        int r = min(rbase + (k << 6) + lane, n_from - 1);   // clamp -> valid
        float4 P = rows[r];
        npx[k] = -2.0f * P.x; npy[k] = -2.0f * P.y; p2[k] = P.z; m[k] = BIGF;
    }

    // group rho bounds from BIN BOUNDARIES (order-independent -- r6 fix)
    int blo_r = min(NBIN - 1, (int)(sqrtf(rows[rbase].z) * BINSCALE));
    int bhi_r = min(NBIN - 1, (int)(sqrtf(rows[min(rbase + RG - 1, n_from - 1)].z) * BINSCALE));
    float rho_lo = (float)blo_r * BINW;          // every row rho >= rho_lo
    float rho_hi = (float)(bhi_r + 1) * BINW;    // every row rho <  rho_hi

    // phase-A window on the ABSOLUTE 64-col batch grid (parity ownership
    // must be consistent across the two z-blocks -> both derive the same
    // [ta0, ta1) from block-z-independent inputs)
    int jmid = (binstart[tc * (NBIN + 1) + blo_r]
                + binstart[tc * (NBIN + 1) + min(bhi_r + 1, NBIN)]) >> 1;
    int tmax = (n_to + 63) >> 6;
    int ta0 = max(0, jmid - AWIN / 2) >> 6;
    int ta1 = min(ta0 + AWIN / 64, tmax);

    __shared__ __align__(16) float bx[NW][64], by[NW][64], bz[NW][64];
    __shared__ float mW[NW][MWS];
    __shared__ float gW[NW];

    auto ld = [&](int t) -> float4 {             // clamped batch element load
        int j = (t << 6) + lane;
        return (j < n_to) ? cols[j] : make_float4(0.0f, 0.0f, BIGF, 0.0f);
    };
    // stage a loaded batch into this wave's LDS stripe; 8 rows/lane against
    // 4 cols per q4 -> 3 ds_read_b128 per 80 VALU (LDS no longer binding).
    // Inner math VERBATIM from the dense kernel -> same bits.
    auto proc = [&](float4 qc) {
        bx[w][lane] = qc.x; by[w][lane] = qc.y; bz[w][lane] = qc.z;
        const float4* X = (const float4*)bx[w];
        const float4* Y = (const float4*)by[w];
        const float4* Z = (const float4*)bz[w];
#pragma unroll
        for (int q4 = 0; q4 < 16; ++q4) {
            float4 qx = X[q4], qy = Y[q4], qz = Z[q4];
#pragma unroll
            for (int k = 0; k < RPT; ++k) {
                float t0 = fmaf(qy.x, npy[k], fmaf(qx.x, npx[k], qz.x));
                float u1 = fmaf(qy.y, npy[k], fmaf(qx.y, npx[k], qz.y));
                m[k] = fminf(m[k], fminf(t0, u1));   // -> v_min3_f32
                float u2 = fmaf(qy.z, npy[k], fmaf(qx.z, npx[k], qz.z));
                float u3 = fmaf(qy.w, npy[k], fmaf(qx.w, npx[k], qz.w));
                m[k] = fminf(m[k], fminf(u2, u3));
            }
        }
    };

    // ---- phase A: parity-z batches of [ta0, ta1), wave-strided (1/wave) ----
    int tA = ta0 + ((ta0 ^ z) & 1);              // first t >= ta0 with t%2==z
    for (int t = tA + 2 * w; t < ta1; t += 2 * NW) proc(ld(t));

    // ---- combine A across waves; per-block bound ----
#pragma unroll
    for (int k = 0; k < RPT; ++k) mW[w][(k << 6) + lane] = m[k];
    __syncthreads();
    int myrow = (w << 6) + lane;                 // row this thread combines
    float cmin = mW[0][myrow];
#pragma unroll
    for (int ww = 1; ww < NW; ++ww) cmin = fminf(cmin, mW[ww][myrow]);
    float md = (rbase + myrow < n_from) ? fmaxf(cmin + p2[w], 0.0f) : -1.0f;
    float g = md;
#pragma unroll
    for (int o = 1; o < 64; o <<= 1) g = fmaxf(g, __shfl_xor(g, o));
    if (lane == 0) gW[w] = g;
    __syncthreads();
    g = gW[0];
#pragma unroll
    for (int ww = 1; ww < NW; ++ww) g = fmaxf(g, gW[ww]);   // block-uniform

    // exclusion bound (r6 margin family, proven absmax==0): this block's
    // window from ITS md; argmin is never excludable (md_z >= true min).
    float S = sqrtf((g + 1.0f) * (1.0f / 0.99f)) * 1.001f;
    int b_lo = max(0, (int)((rho_lo - S) * BINSCALE) - 1);
    int b_hi = min(NBIN, (int)((rho_hi + S) * BINSCALE) + 2);
    int jlo2 = binstart[tc * (NBIN + 1) + b_lo];
    int jhi2 = binstart[tc * (NBIN + 1) + b_hi];
    int tb_lo = jlo2 >> 6;
    int tb_hi = min((jhi2 + 63) >> 6, tmax);

    // parity-z batch lists: left [tb_lo, ta0), right [ta1, tb_hi)
    int tL0 = tb_lo + ((tb_lo ^ z) & 1);
    int nL = max(0, (ta0 - tL0 + 1) >> 1);
    int tR0 = ta1 + ((ta1 ^ z) & 1);
    int nR = max(0, (tb_hi - tR0 + 1) >> 1);
    int nB = nL + nR;
    auto jbB = [&](int u) {
        return (u < nL) ? (tL0 + 2 * u) : (tR0 + 2 * (u - nL));
    };

    // ---- phase B: check-free, register-prefetched (r8 pattern) ----
    float4 qn = (w < nB) ? ld(jbB(w)) : make_float4(0.0f, 0.0f, BIGF, 0.0f);
    for (int u = w; u < nB; u += NW) {
        float4 qc = qn;
        if (u + NW < nB) qn = ld(jbB(u + NW));
        proc(qc);                                // overlap cols: min-idempotent
    }

    // ---- final combine + atomicMin (monotone f: per-part == single-block) --
#pragma unroll
    for (int k = 0; k < RPT; ++k) mW[w][(k << 6) + lane] = m[k];
    __syncthreads();
    float fm = mW[0][myrow];
#pragma unroll
    for (int ww = 1; ww < NW; ++ww) fm = fminf(fm, mW[ww][myrow]);
    int grow = rbase + myrow;
    if (grow < n_from) {
        unsigned int slot = __float_as_uint(rows[grow].w);
        float d2 = fmaxf(fm + p2[w], 0.0f);
        atomicMin(&minarr[combo * HW_ + slot], __float_as_uint(d2));
    }
}

// ---------------- reduce (unchanged: defines the absmax==0 sum order) -------
__global__ void reduce_out_kernel(const int* __restrict__ segcounts,
                                  const unsigned int* __restrict__ minarr,
                                  float* __restrict__ out) {
    int b = blockIdx.x;
    int tid = threadIdx.x;
    int d = tid >> 9;
    int t = tid & 511;
    int combo = b * 2 + d;

    float acc = 0.0f;
    for (int s = 0; s < NSEG; ++s) {
        int c = segcounts[combo * 4 + s];
        const unsigned int* ma = minarr + combo * HW_ + s * SEGCAP;
        for (int r = t; r < c; r += 512)
            acc += sqrtf(fmaxf(__uint_as_float(ma[r]), EPS_));
    }
#pragma unroll
    for (int o = 32; o >= 1; o >>= 1) acc += __shfl_down(acc, o);

    __shared__ float wsum[16];
    if ((tid & 63) == 0) wsum[tid >> 6] = acc;
    __syncthreads();
    if (tid == 0) {
        float s0 = 0.0f, s1 = 0.0f;
#pragma unroll
        for (int w = 0; w < 8; ++w)  s0 += wsum[w];
#pragma unroll
        for (int w = 8; w < 16; ++w) s1 += wsum[w];
        int n0 = 0, n1 = 0;
#pragma unroll
        for (int s = 0; s < NSEG; ++s) {
            n0 += segcounts[(b * 2) * 4 + s];
            n1 += segcounts[(b * 2 + 1) * 4 + s];
        }
        out[b] = (n0 > 0 && n1 > 0)
                 ? s0 / (float)n0 + s1 / (float)n1
                 : 1.0e6f;
    }
}

extern "C" void kernel_launch(void* const* d_in, const int* in_sizes, int n_in,
                              void* d_out, int out_size, void* d_ws, size_t ws_size,
                              hipStream_t stream) {
    const float* in1 = (const float*)d_in[0];
    const float* in2 = (const float*)d_in[1];
    float* out = (float*)d_out;
    char* ws = (char*)d_ws;
    int* segcounts = (int*)ws;
    float4* pts = (float4*)(ws + 256);
    size_t minoff = 256 + (size_t)8 * HW_ * sizeof(float4);
    unsigned int* minarr = (unsigned int*)(ws + minoff);
    size_t sortoff = minoff + (size_t)8 * HW_ * sizeof(unsigned int);
    float4* sorted = (float4*)(ws + sortoff);
    size_t binoff = sortoff + (size_t)8 * HW_ * sizeof(float4);
    int* binstart = (int*)(ws + binoff);
    size_t histoff = binoff + (size_t)8 * (NBIN + 1) * sizeof(int);
    int* histG = (int*)(ws + histoff);

    hipLaunchKernelGGL(compact_kernel, dim3(NSEG, 8), dim3(1024), 0, stream,
                       in1, in2, segcounts, pts, (uint4*)minarr, histG);
    hipLaunchKernelGGL(scatter_kernel, dim3(NSEG, 8), dim3(512), 0, stream,
                       segcounts, pts, histG, sorted, binstart);
    hipLaunchKernelGGL(pdist_kernel, dim3(PD_NGRP, 8, 2), dim3(512), 0, stream,
                       sorted, binstart, minarr);
    hipLaunchKernelGGL(reduce_out_kernel, dim3(B_), dim3(1024), 0, stream,
                       segcounts, minarr, out);
}

// Round 10
// 95.218 us; speedup vs baseline: 1.0901x; 1.0901x over previous
//
#include <hip/hip_runtime.h>
#include <math.h>

// Chamfer distance, B=4, H=W=128, HW=16384, threshold 0.1.
//
// r9 post-mortem: RG=512 + parity-split phase A regressed (83.7->103.8,
// absmax still 0.0 -- the parity/bound/atomicMin machinery is proven).
// Window economics broke: 512-row span + md over 512 rows + half-density
// phase A (md from n/2 candidates => S x1.4) => more total col-visits.
// r10: RG=256 (4 rows/lane = 2x LDS relief vs r8), phase A FULL in both
// z-blocks (identical, block-z-independent => identical S/window; dup A is
// ~16 batches, min-idempotent), phase B parity-split. p2 moved to LDS
// (r9's p2[w] runtime index = scratch, rule #20). Combine: atomicMin of
// fmax(min_z+p2,0) == fmax(min(A u B)+p2,0) (monotone) == dense bits.
//
// ws layout (~4.7 MB):
//   [0,128)    int segcounts[8][4]
//   [256,+2MB) float4 pts[8][HW]     segmented semi-dense (seg s at s*4096)
//   [+512KB)   uint minarr[8][HW]    d^2 bits, slot-indexed
//   [+2MB)     float4 sorted[8][HW]  (x, y, z, slot_bits) rho-bucket order
//   [+8.2KB)   int binstart[8][257]
//   [+32KB)    int hist[8][4][256]

#define B_ 4
#define HW_ 16384
#define THRESH 0.1f
#define BIGF 1e30f
#define EPS_ 1e-12f

#define SEGCAP 4096
#define NSEG 4
#define NBIN 256
#define BINSCALE 0.25f   // bin = min(255, rho*0.25); width 4, covers rho<1024
#define BINW 4.0f
#define RG 256           // rows per pdist block (4/lane)
#define RPT 4            // rows per thread
#define NW 8             // waves per pdist block (512 threads)
#define AWIN 1024        // phase-A window (cols), 16 batches on the 64-grid
#define PD_NGRP 64       // 64 x 256 = 16384 row-slot coverage
#define MWS 264          // mW stride (264%32=8 -> combine reads conflict-lite)

// ---------------- compact + bin histogram (r6, proven) ----------------
__global__ __launch_bounds__(1024)
void compact_kernel(const float* __restrict__ in1, const float* __restrict__ in2,
                    int* __restrict__ segcounts, float4* __restrict__ pts,
                    uint4* __restrict__ minarr4, int* __restrict__ histG) {
    int seg = blockIdx.x, combo = blockIdx.y;
    int b = combo >> 1, s = combo & 1;
    int tid = threadIdx.x, lane = tid & 63, wid = tid >> 6;
    const float* in = s ? in2 : in1;
    int ibase = seg * SEGCAP + tid * 4;
    float4 v = ((const float4*)(in + b * HW_))[(unsigned)ibase >> 2];
    float w0 = v.x - THRESH, w1 = v.y - THRESH, w2 = v.z - THRESH, w3 = v.w - THRESH;
    int a0 = w0 > 0.f, a1 = w1 > 0.f, a2 = w2 > 0.f, a3 = w3 > 0.f;

    unsigned int bb = __float_as_uint(BIGF);
    minarr4[(unsigned)(combo * HW_ + ibase) >> 2] = make_uint4(bb, bb, bb, bb);

    __shared__ int hist[NBIN];
    if (tid < NBIN) hist[tid] = 0;

    int c = a0 + a1 + a2 + a3;
    int incl = c;
#pragma unroll
    for (int o = 1; o < 64; o <<= 1) {
        int x = __shfl_up(incl, o, 64);
        if (lane >= o) incl += x;
    }
    int wexcl = incl - c;
    __shared__ int wtot[16], wpre[17];
    if (lane == 63) wtot[wid] = incl;
    __syncthreads();                             // covers hist init too
    if (tid == 0) {
        int run = 0;
#pragma unroll
        for (int ww = 0; ww < 16; ++ww) { wpre[ww] = run; run += wtot[ww]; }
        wpre[16] = run;
    }
    __syncthreads();
    int off = wpre[wid] + wexcl;
    float4* dst = pts + combo * HW_ + seg * SEGCAP;
    float wv[4] = {w0, w1, w2, w3};
    int   av[4] = {a0, a1, a2, a3};
#pragma unroll
    for (int u = 0; u < 4; ++u) {
        if (av[u]) {
            int i = ibase + u;
            float qx = (float)(i >> 7) * wv[u];
            float qy = (float)(i & 127) * wv[u];
            float zz = qx * qx + qy * qy;
            dst[off] = make_float4(qx, qy, zz, 0.0f);
            int bin = min(NBIN - 1, (int)(sqrtf(zz) * BINSCALE));
            atomicAdd(&hist[bin], 1);
            ++off;
        }
    }
    if (tid == 0) segcounts[combo * 4 + seg] = wpre[16];
    __syncthreads();
    if (tid < NBIN)
        histG[(combo * NSEG + seg) * NBIN + tid] = hist[tid];
}

// ---------------- scatter: 1 block per (seg, combo) = 32 blocks (r6) -------
__global__ __launch_bounds__(512)
void scatter_kernel(const int* __restrict__ segcounts, const float4* __restrict__ pts,
                    const int* __restrict__ histG, float4* __restrict__ sorted,
                    int* __restrict__ binstartG) {
    int seg = blockIdx.x, combo = blockIdx.y;
    int tid = threadIdx.x;
    __shared__ int h[NSEG][NBIN];
    __shared__ int sc[NBIN];
    __shared__ int cur[NBIN];
    for (int i = tid; i < NSEG * NBIN; i += 512)
        h[i >> 8][i & 255] = histG[combo * NSEG * NBIN + i];
    __syncthreads();
    if (tid < NBIN) sc[tid] = h[0][tid] + h[1][tid] + h[2][tid] + h[3][tid];
    __syncthreads();
#pragma unroll
    for (int o = 1; o < NBIN; o <<= 1) {         // Hillis-Steele inclusive scan
        int v = (tid < NBIN && tid >= o) ? sc[tid - o] : 0;
        __syncthreads();
        if (tid < NBIN) sc[tid] += v;
        __syncthreads();
    }
    if (tid < NBIN) {
        int tot = h[0][tid] + h[1][tid] + h[2][tid] + h[3][tid];
        int excl = sc[tid] - tot;                // exclusive bin start
        int o2 = excl;
        for (int s2 = 0; s2 < seg; ++s2) o2 += h[s2][tid];   // seg-uniform
        cur[tid] = o2;
        if (seg == 0) binstartG[combo * (NBIN + 1) + tid] = excl;
    }
    if (seg == 0 && tid == 0)
        binstartG[combo * (NBIN + 1) + NBIN] = sc[NBIN - 1];  // n_active
    __syncthreads();
    int c = segcounts[combo * 4 + seg];
    const float4* src = pts + combo * HW_ + seg * SEGCAP;
    for (int i = tid; i < c; i += 512) {
        float4 p = src[i];
        int bin = min(NBIN - 1, (int)(sqrtf(p.z) * BINSCALE));
        int idx = atomicAdd(&cur[bin], 1);
        sorted[(size_t)combo * HW_ + idx] =
            make_float4(p.x, p.y, p.z, __uint_as_float((unsigned)(seg * SEGCAP + i)));
    }
}

// ---------------- pruned dist: 256 rows, 4 rows/lane, B-only parity split ---
__global__ __launch_bounds__(512, 4)   // VGPR cap 128; ~12 row-state regs
void pdist_kernel(const float4* __restrict__ sorted, const int* __restrict__ binstart,
                  unsigned int* __restrict__ minarr) {
    int grp = blockIdx.x, combo = blockIdx.y, z = blockIdx.z;
    int tid = threadIdx.x, lane = tid & 63, w = tid >> 6;
    int tc = combo ^ 1;
    int n_from = binstart[combo * (NBIN + 1) + NBIN];
    int n_to   = binstart[tc * (NBIN + 1) + NBIN];
    if (n_from <= 0 || n_to <= 0) return;        // reduce_out emits sentinel
    int rbase = grp * RG;
    if (rbase >= n_from) return;                 // block-uniform

    const float4* __restrict__ rows = sorted + (size_t)combo * HW_;
    const float4* __restrict__ cols = sorted + (size_t)tc * HW_;

    __shared__ __align__(16) float bx[NW][64], by[NW][64], bz[NW][64];
    __shared__ float mW[NW][MWS];
    __shared__ float p2s[RG];
    __shared__ float gS;

    // every wave holds ALL 256 group rows (4/lane); wave 0 stashes |p|^2
    float npx[RPT], npy[RPT], m[RPT];
#pragma unroll
    for (int k = 0; k < RPT; ++k) {
        int r = min(rbase + (k << 6) + lane, n_from - 1);   // clamp -> valid
        float4 P = rows[r];
        npx[k] = -2.0f * P.x; npy[k] = -2.0f * P.y; m[k] = BIGF;
        if (w == 0) p2s[(k << 6) + lane] = P.z;
    }

    // group rho bounds from BIN BOUNDARIES (order-independent -- r6 fix)
    int blo_r = min(NBIN - 1, (int)(sqrtf(rows[rbase].z) * BINSCALE));
    int bhi_r = min(NBIN - 1, (int)(sqrtf(rows[min(rbase + RG - 1, n_from - 1)].z) * BINSCALE));
    float rho_lo = (float)blo_r * BINW;          // every row rho >= rho_lo
    float rho_hi = (float)(bhi_r + 1) * BINW;    // every row rho <  rho_hi

    // phase-A window on the ABSOLUTE 64-col batch grid; all inputs are
    // block-z-independent -> BOTH z-blocks compute the identical window,
    // md, S (full-density A fixes r9's sqrt2 md inflation)
    int jmid = (binstart[tc * (NBIN + 1) + blo_r]
                + binstart[tc * (NBIN + 1) + min(bhi_r + 1, NBIN)]) >> 1;
    int tmax = (n_to + 63) >> 6;
    int ta0 = max(0, jmid - AWIN / 2) >> 6;
    int ta1 = min(ta0 + AWIN / 64, tmax);

    auto ld = [&](int t) -> float4 {             // clamped batch element load
        int j = (t << 6) + lane;
        return (j < n_to) ? cols[j] : make_float4(0.0f, 0.0f, BIGF, 0.0f);
    };
    // stage a loaded batch into this wave's LDS stripe; 4 rows/lane vs 4
    // cols per q4 -> 3 ds_read_b128 per 40 VALU (VALU-bound at CU level).
    // Inner math VERBATIM from the dense kernel -> same bits.
    auto proc = [&](float4 qc) {
        bx[w][lane] = qc.x; by[w][lane] = qc.y; bz[w][lane] = qc.z;
        const float4* X = (const float4*)bx[w];
        const float4* Y = (const float4*)by[w];
        const float4* Z = (const float4*)bz[w];
#pragma unroll
        for (int q4 = 0; q4 < 16; ++q4) {
            float4 qx = X[q4], qy = Y[q4], qz = Z[q4];
#pragma unroll
            for (int k = 0; k < RPT; ++k) {
                float t0 = fmaf(qy.x, npy[k], fmaf(qx.x, npx[k], qz.x));
                float u1 = fmaf(qy.y, npy[k], fmaf(qx.y, npx[k], qz.y));
                m[k] = fminf(m[k], fminf(t0, u1));   // -> v_min3_f32
                float u2 = fmaf(qy.z, npy[k], fmaf(qx.z, npx[k], qz.z));
                float u3 = fmaf(qy.w, npy[k], fmaf(qx.w, npx[k], qz.w));
                m[k] = fminf(m[k], fminf(u2, u3));
            }
        }
    };

    // ---- phase A: FULL window in every z-block, wave-strided, prefetched --
    float4 qn = (ta0 + w < ta1) ? ld(ta0 + w)
                                : make_float4(0.0f, 0.0f, BIGF, 0.0f);
    for (int t = ta0 + w; t < ta1; t += NW) {
        float4 qc = qn;
        if (t + NW < ta1) qn = ld(t + NW);       // hide under FMAs
        proc(qc);
    }

    // ---- combine A across waves; block-uniform bound (== other z-block) ----
#pragma unroll
    for (int k = 0; k < RPT; ++k) mW[w][(k << 6) + lane] = m[k];
    __syncthreads();
    float g = -1.0f;
    if (tid < RG) {
        float cmin = mW[0][tid];
#pragma unroll
        for (int ww = 1; ww < NW; ++ww) cmin = fminf(cmin, mW[ww][tid]);
        g = (rbase + tid < n_from) ? fmaxf(cmin + p2s[tid], 0.0f) : -1.0f;
    }
#pragma unroll
    for (int o = 1; o < 64; o <<= 1) g = fmaxf(g, __shfl_xor(g, o));
    if (tid == 0) gS = g;                        // wave0 covers rows 0-63; need
    __syncthreads();                             // block max:
    if ((tid & 63) == 0 && tid < RG) {           // lanes0 of waves 0-3 hold
        // each wave's 64-row max; fold via atomic-free LDS max sequence
    }
    // block max of the 4 row-wave maxima (waves 0-3 computed g over their
    // 64 rows; waves 4-7 have g=-1). Simple: every thread's g -> mW[0][..]
    if ((tid & 63) == 0) mW[w][MWS - 1] = g;     // per-wave lane0 max
    __syncthreads();
    g = mW[0][MWS - 1];
#pragma unroll
    for (int ww = 1; ww < NW; ++ww) g = fmaxf(g, mW[ww][MWS - 1]);
    // g now block-uniform and identical across z-blocks

    // exclusion bound (r6 margin family, proven absmax==0): argmin col is
    // never excludable (md >= true min) -> parity owner processes it.
    float S = sqrtf((g + 1.0f) * (1.0f / 0.99f)) * 1.001f;
    int b_lo = max(0, (int)((rho_lo - S) * BINSCALE) - 1);
    int b_hi = min(NBIN, (int)((rho_hi + S) * BINSCALE) + 2);
    int jlo2 = binstart[tc * (NBIN + 1) + b_lo];
    int jhi2 = binstart[tc * (NBIN + 1) + b_hi];
    int tb_lo = jlo2 >> 6;
    int tb_hi = min((jhi2 + 63) >> 6, tmax);

    // parity-z residual batch lists: left [tb_lo, ta0), right [ta1, tb_hi)
    int tL0 = tb_lo + ((tb_lo ^ z) & 1);
    int nL = max(0, (ta0 - tL0 + 1) >> 1);
    int tR0 = ta1 + ((ta1 ^ z) & 1);
    int nR = max(0, (tb_hi - tR0 + 1) >> 1);
    int nB = nL + nR;
    auto jbB = [&](int u) {
        return (u < nL) ? (tL0 + 2 * u) : (tR0 + 2 * (u - nL));
    };

    // ---- phase B: check-free, register-prefetched (r8 pattern) ----
    qn = (w < nB) ? ld(jbB(w)) : make_float4(0.0f, 0.0f, BIGF, 0.0f);
    for (int u = w; u < nB; u += NW) {
        float4 qc = qn;
        if (u + NW < nB) qn = ld(jbB(u + NW));
        proc(qc);                                // overlap cols: min-idempotent
    }

    // ---- final combine + atomicMin (monotone f: per-part == single-block) --
    __syncthreads();                             // phase-A mW reads all done
#pragma unroll
    for (int k = 0; k < RPT; ++k) mW[w][(k << 6) + lane] = m[k];
    __syncthreads();
    if (tid < RG && rbase + tid < n_from) {
        float fm = mW[0][tid];
#pragma unroll
        for (int ww = 1; ww < NW; ++ww) fm = fminf(fm, mW[ww][tid]);
        unsigned int slot = __float_as_uint(rows[rbase + tid].w);
        float d2 = fmaxf(fm + p2s[tid], 0.0f);
        atomicMin(&minarr[combo * HW_ + slot], __float_as_uint(d2));
    }
}

// ---------------- reduce (unchanged: defines the absmax==0 sum order) -------
__global__ void reduce_out_kernel(const int* __restrict__ segcounts,
                                  const unsigned int* __restrict__ minarr,
                                  float* __restrict__ out) {
    int b = blockIdx.x;
    int tid = threadIdx.x;
    int d = tid >> 9;
    int t = tid & 511;
    int combo = b * 2 + d;

    float acc = 0.0f;
    for (int s = 0; s < NSEG; ++s) {
        int c = segcounts[combo * 4 + s];
        const unsigned int* ma = minarr + combo * HW_ + s * SEGCAP;
        for (int r = t; r < c; r += 512)
            acc += sqrtf(fmaxf(__uint_as_float(ma[r]), EPS_));
    }
#pragma unroll
    for (int o = 32; o >= 1; o >>= 1) acc += __shfl_down(acc, o);

    __shared__ float wsum[16];
    if ((tid & 63) == 0) wsum[tid >> 6] = acc;
    __syncthreads();
    if (tid == 0) {
        float s0 = 0.0f, s1 = 0.0f;
#pragma unroll
        for (int w = 0; w < 8; ++w)  s0 += wsum[w];
#pragma unroll
        for (int w = 8; w < 16; ++w) s1 += wsum[w];
        int n0 = 0, n1 = 0;
#pragma unroll
        for (int s = 0; s < NSEG; ++s) {
            n0 += segcounts[(b * 2) * 4 + s];
            n1 += segcounts[(b * 2 + 1) * 4 + s];
        }
        out[b] = (n0 > 0 && n1 > 0)
                 ? s0 / (float)n0 + s1 / (float)n1
                 : 1.0e6f;
    }
}

extern "C" void kernel_launch(void* const* d_in, const int* in_sizes, int n_in,
                              void* d_out, int out_size, void* d_ws, size_t ws_size,
                              hipStream_t stream) {
    const float* in1 = (const float*)d_in[0];
    const float* in2 = (const float*)d_in[1];
    float* out = (float*)d_out;
    char* ws = (char*)d_ws;
    int* segcounts = (int*)ws;
    float4* pts = (float4*)(ws + 256);
    size_t minoff = 256 + (size_t)8 * HW_ * sizeof(float4);
    unsigned int* minarr = (unsigned int*)(ws + minoff);
    size_t sortoff = minoff + (size_t)8 * HW_ * sizeof(unsigned int);
    float4* sorted = (float4*)(ws + sortoff);
    size_t binoff = sortoff + (size_t)8 * HW_ * sizeof(float4);
    int* binstart = (int*)(ws + binoff);
    size_t histoff = binoff + (size_t)8 * (NBIN + 1) * sizeof(int);
    int* histG = (int*)(ws + histoff);

    hipLaunchKernelGGL(compact_kernel, dim3(NSEG, 8), dim3(1024), 0, stream,
                       in1, in2, segcounts, pts, (uint4*)minarr, histG);
    hipLaunchKernelGGL(scatter_kernel, dim3(NSEG, 8), dim3(512), 0, stream,
                       segcounts, pts, histG, sorted, binstart);
    hipLaunchKernelGGL(pdist_kernel, dim3(PD_NGRP, 8, 2), dim3(512), 0, stream,
                       sorted, binstart, minarr);
    hipLaunchKernelGGL(reduce_out_kernel, dim3(B_), dim3(1024), 0, stream,
                       segcounts, minarr, out);
}